// Round 3
// baseline (13710.559 us; speedup 1.0000x reference)
//
#include <hip/hip_runtime.h>
#include <math.h>

#define BB 512
#define LCC 128
#define LAA 16
#define D2 600
#define NT 80
#define KT 10
#define NP 1280
#define TC 4

typedef __attribute__((ext_vector_type(8))) short bf16x8;
typedef __attribute__((ext_vector_type(4))) float f32x4;

__device__ __forceinline__ float sigf(float x){ return 1.0f/(1.0f+expf(-x)); }
__device__ __forceinline__ unsigned short f2bf(float f){
  unsigned u = __float_as_uint(f);
  unsigned r = (u + 0x7FFFu + ((u>>16)&1u)) >> 16;
  return (unsigned short)r;
}
__device__ __forceinline__ float bf2f(unsigned short h){ return __uint_as_float(((unsigned)h)<<16); }

// ---------------- lengths ----------------
__global__ void k_lengths(const int* __restrict__ traw, const int* __restrict__ tasp,
                          const int* __restrict__ tleft,
                          int* __restrict__ clen, int* __restrict__ alen, int* __restrict__ sstart){
  int b = blockIdx.x*blockDim.x + threadIdx.x;
  if (b >= BB) return;
  int c=0,a=0,l=0;
  for (int t=0;t<LCC;t++) c += (traw[b*LCC+t]!=0);
  for (int t=0;t<LAA;t++) a += (tasp[b*LAA+t]!=0);
  for (int t=0;t<LCC;t++) l += (tleft[b*LCC+t]!=0);
  clen[b]=c; alen[b]=a; sstart[b]=l;
}

// ---------------- MFMA weight fragments ----------------
// W[1200][300] -> Wfrag[m][pass(hi/lo)][nt<80][kt<10][lane<64][e<8] bf16
// n' (gate-interleaved) = nt*16 + (lane&15); orig n = 300*(n'&3) + (n'>>2)
// k = kt*32 + 4*(lane>>4) + (e&3) + 16*(e>>2)   (same map used for A staging -> permutation cancels)
__global__ void k_prep_frag(const float* __restrict__ cWif,const float* __restrict__ cWhf,
                            const float* __restrict__ cWib,const float* __restrict__ cWhb,
                            const float* __restrict__ aWif,const float* __restrict__ aWhf,
                            const float* __restrict__ aWib,const float* __restrict__ aWhb,
                            short* __restrict__ Wfrag){
  const int m = blockIdx.y;
  const float* W;
  switch(m){ case 0:W=cWif;break; case 1:W=cWhf;break; case 2:W=cWib;break; case 3:W=cWhb;break;
             case 4:W=aWif;break; case 5:W=aWhf;break; case 6:W=aWib;break; default:W=aWhb;break; }
  const int nt = blockIdx.x/KT, kt = blockIdx.x%KT;
  const int lane = threadIdx.x;
  const int np = nt*16 + (lane&15);
  const int g  = lane>>4;
  const int n  = (np<1200) ? 300*(np&3) + (np>>2) : -1;
  size_t bi_hi = (((((size_t)m*2+0)*NT + nt)*KT + kt)*64 + lane)*8;
  size_t bi_lo = (((((size_t)m*2+1)*NT + nt)*KT + kt)*64 + lane)*8;
  #pragma unroll
  for (int e=0;e<8;++e){
    int k = kt*32 + 4*g + (e&3) + 16*(e>>2);
    float v = (n>=0 && k<300) ? W[(size_t)n*300+k] : 0.f;
    unsigned short hi = f2bf(v);
    float lo = v - bf2f(hi);
    Wfrag[bi_hi+e] = (short)hi;
    Wfrag[bi_lo+e] = (short)f2bf(lo);
  }
}

// bias permuted to n' order, padded to 1280
__global__ void k_prep_bias(const float* __restrict__ cbf,const float* __restrict__ cbb,
                            const float* __restrict__ abf,const float* __restrict__ abb,
                            float* __restrict__ bias_p){
  int j = blockIdx.x;
  int np = blockIdx.y*256 + threadIdx.x;
  if (np>=NP) return;
  const float* b = (j==0)?cbf:(j==1)?cbb:(j==2)?abf:abb;
  bias_p[j*NP+np] = (np<1200) ? b[300*(np&3)+(np>>2)] : 0.f;
}

// ---------------- MFMA BiLSTM recurrence ----------------
// 128 blocks, 512 thr. job=(bid&7)>>1 -> one job per XCD (L2 holds that job's fragments).
// 16 batch rows/block. Per 4-step chunk: batched xg GEMM (x.Wi+b, split-bf16) -> global scratch (bf16);
// per step: split-bf16 MFMA Wh.h -> gs(LDS f32) -> gate update -> h back to bf16 A-fragments in LDS.
__launch_bounds__(512,1)
__global__ void k_rec_mfma(const int* __restrict__ traw, const int* __restrict__ tasp,
                           const float* __restrict__ embed,
                           const short* __restrict__ Wfrag, const float* __restrict__ bias_p,
                           const int* __restrict__ clen, const int* __restrict__ alen,
                           const int* __restrict__ sstart,
                           short* __restrict__ xg_all,
                           float* __restrict__ ctx_out, float* __restrict__ asp_out)
{
  const int tid = threadIdx.x;
  const int lane = tid & 63;
  const int wv = tid >> 6;
  const int bid = blockIdx.x;
  const int xcd = bid & 7;
  const int job = xcd >> 1;
  const int wj  = (bid >> 3)*2 + (xcd & 1);   // 0..31
  const int row0 = wj*16;
  const int isCtx = (job<2), bwd = (job&1);
  const int T = isCtx ? LCC : LAA;
  const int* lenp = isCtx ? clen : alen;
  const int* tokp = isCtx ? traw : tasp;
  float* outb = isCtx ? ctx_out : asp_out;
  const int coloff = bwd ? 300 : 0;
  const short* WiF = Wfrag + (size_t)(job*2+0)*819200;
  const short* WhF = Wfrag + (size_t)(job*2+1)*819200;
  short* xg = xg_all + (size_t)bid * (16*TC*NP);

  __shared__ short hfrag[KT][64][8];     // h in A-fragment layout (k-pad zeroed)
  __shared__ float gs[16][1284];         // Wh.h pre-acts; pad 1284 -> 2-way-free banks
  __shared__ int   tok_s[16][LCC];
  __shared__ float biasL[NP];
  __shared__ int   len_s[16];
  __shared__ float wins[16], wine[16], winl[16];
  short* stg = (short*)&gs[0][0];        // chunk A-staging alias: [TC][KT][64][8] = 40KB < 82KB

  for (int i=tid; i<16*T; i+=512){ int r=i/T, t=i-r*T; tok_s[r][t]=tokp[(row0+r)*T+t]; }
  if (tid<16){
    int b=row0+tid; len_s[tid]=lenp[b];
    if (isCtx){ float s=(float)sstart[b], a=(float)alen[b];
      wins[tid]=s; wine[tid]=s+a-1.0f; winl[tid]=(float)LCC - a; }
  }
  for (int i=tid;i<NP;i+=512) biasL[i]=bias_p[job*NP+i];
  for (int i=tid;i<KT*64*8;i+=512) ((short*)hfrag)[i]=0;
  float cst[10];
  #pragma unroll
  for (int s=0;s<10;++s) cst[s]=0.f;
  __syncthreads();
  int maxl=0;
  #pragma unroll
  for (int r=0;r<16;++r) maxl = max(maxl, len_s[r]);

  const int nt0 = wv*10;
  const int col = lane & 15, lg = lane >> 4;

  for (int t0=0; t0<maxl; t0+=TC){
    // ---- stage x A-fragments for the 4 chunk timesteps ----
    {
      const int tc = wv & 3, kth = wv >> 2;
      const int t = t0 + tc;
      const int r = col;
      const int L = len_s[r];
      int pos = bwd ? (L-1-t) : t;
      if (t >= L) pos = 0;                       // dead rows: any valid token
      const float* erow = embed + (size_t)tok_s[r][pos]*300;
      for (int kt=kth*5; kt<kth*5+5; ++kt){
        const int k0 = kt*32 + 4*lg;
        float4 pa = {0.f,0.f,0.f,0.f}, pb = {0.f,0.f,0.f,0.f};
        if (k0+3  < 300) pa = *(const float4*)(erow + k0);
        if (k0+19 < 300) pb = *(const float4*)(erow + k0 + 16);
        bf16x8 pk;
        pk[0]=(short)f2bf(pa.x); pk[1]=(short)f2bf(pa.y); pk[2]=(short)f2bf(pa.z); pk[3]=(short)f2bf(pa.w);
        pk[4]=(short)f2bf(pb.x); pk[5]=(short)f2bf(pb.y); pk[6]=(short)f2bf(pb.z); pk[7]=(short)f2bf(pb.w);
        ((bf16x8*)stg)[(tc*KT + kt)*64 + lane] = pk;
      }
    }
    __syncthreads();
    // ---- chunk GEMM: xg = x.Wi + b (2-pass split-bf16), store bf16 ----
    {
      f32x4 acc[4][10];
      #pragma unroll
      for (int m=0;m<4;++m){
        #pragma unroll
        for (int i=0;i<10;++i) acc[m][i] = (f32x4){0.f,0.f,0.f,0.f};
      }
      #pragma unroll
      for (int pass=0; pass<2; ++pass){
        const bf16x8* B = (const bf16x8*)(WiF + (size_t)pass*409600);
        for (int kt=0; kt<KT; ++kt){
          bf16x8 a0 = ((const bf16x8*)stg)[(0*KT+kt)*64 + lane];
          bf16x8 a1 = ((const bf16x8*)stg)[(1*KT+kt)*64 + lane];
          bf16x8 a2 = ((const bf16x8*)stg)[(2*KT+kt)*64 + lane];
          bf16x8 a3 = ((const bf16x8*)stg)[(3*KT+kt)*64 + lane];
          #pragma unroll
          for (int ntl=0; ntl<10; ++ntl){
            bf16x8 bb = B[(size_t)((nt0+ntl)*KT + kt)*64 + lane];
            acc[0][ntl] = __builtin_amdgcn_mfma_f32_16x16x32_bf16(a0, bb, acc[0][ntl], 0,0,0);
            acc[1][ntl] = __builtin_amdgcn_mfma_f32_16x16x32_bf16(a1, bb, acc[1][ntl], 0,0,0);
            acc[2][ntl] = __builtin_amdgcn_mfma_f32_16x16x32_bf16(a2, bb, acc[2][ntl], 0,0,0);
            acc[3][ntl] = __builtin_amdgcn_mfma_f32_16x16x32_bf16(a3, bb, acc[3][ntl], 0,0,0);
          }
        }
      }
      #pragma unroll
      for (int ntl=0; ntl<10; ++ntl){
        int np = (nt0+ntl)*16 + col;
        float bv = biasL[np];
        #pragma unroll
        for (int m=0;m<4;++m){
          #pragma unroll
          for (int q=0;q<4;++q){
            int r = lg*4 + q;                    // C/D: col=lane&15, row=(lane>>4)*4+q (m89-verified)
            xg[((size_t)r*TC + m)*NP + np] = (short)f2bf(acc[m][ntl][q] + bv);
          }
        }
      }
    }
    __syncthreads();
    // ---- recurrent steps ----
    const int tend = min(TC, maxl - t0);
    for (int tc=0; tc<tend; ++tc){
      const int t = t0 + tc;
      f32x4 ga[10];
      #pragma unroll
      for (int i=0;i<10;++i) ga[i] = (f32x4){0.f,0.f,0.f,0.f};
      #pragma unroll
      for (int pass=0; pass<2; ++pass){
        const bf16x8* B = (const bf16x8*)(WhF + (size_t)pass*409600);
        for (int kt=0; kt<KT; ++kt){
          bf16x8 a = *(const bf16x8*)&hfrag[kt][lane][0];
          #pragma unroll
          for (int ntl=0; ntl<10; ++ntl){
            bf16x8 bb = B[(size_t)((nt0+ntl)*KT + kt)*64 + lane];
            ga[ntl] = __builtin_amdgcn_mfma_f32_16x16x32_bf16(a, bb, ga[ntl], 0,0,0);
          }
        }
      }
      #pragma unroll
      for (int ntl=0; ntl<10; ++ntl){
        int np = (nt0+ntl)*16 + col;
        #pragma unroll
        for (int q=0;q<4;++q) gs[lg*4+q][np] = ga[ntl][q];
      }
      __syncthreads();
      // gate update: thread owns fixed (r,j) pairs; c in regs
      #pragma unroll
      for (int s=0;s<10;++s){
        int idx = tid + s*512;
        if (idx < 4800){
          int r = idx/300, j = idx - r*300;
          int L = len_s[r];
          if (t < L){
            float4 gq = *(const float4*)&gs[r][4*j];
            // agent-scope load bypasses L1 (per-block xg scratch is rewritten every chunk)
            unsigned long long raw = __hip_atomic_load(
              (const unsigned long long*)(xg + ((size_t)r*TC + tc)*NP + 4*j),
              __ATOMIC_RELAXED, __HIP_MEMORY_SCOPE_AGENT);
            float gi = gq.x + bf2f((unsigned short)( raw        & 0xFFFF));
            float gf = gq.y + bf2f((unsigned short)((raw >> 16) & 0xFFFF));
            float gg2= gq.z + bf2f((unsigned short)((raw >> 32) & 0xFFFF));
            float go = gq.w + bf2f((unsigned short)((raw >> 48) & 0xFFFF));
            float cn = sigf(gf)*cst[s] + sigf(gi)*tanhf(gg2);
            float hn = sigf(go)*tanhf(cn);
            cst[s] = cn;
            int kt2 = j>>5, kk = j&31;
            int g2 = (kk&15)>>2, e = (kk&3) + 4*(kk>>4);
            hfrag[kt2][g2*16 + r][e] = (short)f2bf(hn);
            int tpos = bwd ? (L-1-t) : t;
            float wgt = 1.0f;
            if (isCtx){
              float jf=(float)tpos, s_=wins[r], e_=wine[r], sl=winl[r];
              wgt = (jf<s_)?(1.0f-(s_-jf)/sl):((jf<=e_)?0.0f:(1.0f-(jf-e_)/sl));
            }
            outb[((size_t)(row0+r)*T + tpos)*(size_t)D2 + coloff + j] = hn*wgt;
          }
        }
      }
      __syncthreads();
    }
  }
}

// ================= fallback f32 path (round-2, verified) =================
__global__ void k_prep_f32(const float* __restrict__ cWif,const float* __restrict__ cWhf,
                           const float* __restrict__ cWib,const float* __restrict__ cWhb,
                           const float* __restrict__ aWif,const float* __restrict__ aWhf,
                           const float* __restrict__ aWib,const float* __restrict__ aWhb,
                           float* __restrict__ WT4){
  const int m = blockIdx.z;
  const float* src;
  switch(m){
    case 0: src=cWif; break; case 1: src=cWhf; break;
    case 2: src=cWib; break; case 3: src=cWhb; break;
    case 4: src=aWif; break; case 5: src=aWhf; break;
    case 6: src=aWib; break; default: src=aWhb; break;
  }
  int rem = blockIdx.x*blockDim.x + threadIdx.x;
  if (rem >= 90000) return;
  int kq = rem/1200, n = rem - kq*1200;
  float4 v = *(const float4*)(src + (size_t)n*300 + kq*4);
  ((float4*)WT4)[(size_t)m*90000 + rem] = v;
}

__device__ __forceinline__ void kloop8(const float (*__restrict__ src)[300],
                                       const float* __restrict__ W,
                                       float* a0, float* a1, float* a2,
                                       int n0, int n1, int n2, bool has3){
  const float4* Wp = (const float4*)W;
  for (int kq=0; kq<75; ++kq){
    float4 w0 = Wp[n0];
    float4 w1 = Wp[n1];
    #pragma unroll
    for (int r=0;r<8;r++){
      float4 h4 = *(const float4*)&src[r][4*kq];
      a0[r]=fmaf(w0.w,h4.w,fmaf(w0.z,h4.z,fmaf(w0.y,h4.y,fmaf(w0.x,h4.x,a0[r]))));
      a1[r]=fmaf(w1.w,h4.w,fmaf(w1.z,h4.z,fmaf(w1.y,h4.y,fmaf(w1.x,h4.x,a1[r]))));
    }
    if (has3){
      float4 w2 = Wp[n2];
      #pragma unroll
      for (int r=0;r<8;r++){
        float4 h4 = *(const float4*)&src[r][4*kq];
        a2[r]=fmaf(w2.w,h4.w,fmaf(w2.z,h4.z,fmaf(w2.y,h4.y,fmaf(w2.x,h4.x,a2[r]))));
      }
    }
    Wp += 1200;
  }
}

__launch_bounds__(512,1)
__global__ void k_rec_f32(const int* __restrict__ traw, const int* __restrict__ tasp,
                          const float* __restrict__ embed,
                          const float* __restrict__ WT4,
                          const float* __restrict__ cbf, const float* __restrict__ cbb,
                          const float* __restrict__ abf, const float* __restrict__ abb,
                          const int* __restrict__ clen, const int* __restrict__ alen,
                          const int* __restrict__ sstart,
                          float* __restrict__ ctx_out, float* __restrict__ asp_out)
{
  const int tid = threadIdx.x;
  const int job = blockIdx.x & 3;
  const int sub = blockIdx.x >> 2;
  const int row0 = sub*8;
  const int isCtx = (job < 2), bwd = (job & 1);
  const int T = isCtx ? LCC : LAA;
  const int* lenp = isCtx ? clen : alen;
  const int* tokp = isCtx ? traw : tasp;
  const float* Wi = WT4 + (size_t)(job*2)*360000;
  const float* Wh = Wi + 360000;
  const float* bias = (job==0)?cbf:(job==1)?cbb:(job==2)?abf:abb;
  float* outb = isCtx ? ctx_out : asp_out;
  const int coloff = bwd ? 300 : 0;

  __shared__ __align__(16) float hb[2][8][300];
  __shared__ __align__(16) float xb[8][300];
  __shared__ float gsf[8][1200];
  __shared__ int  tok_s2[8][LCC];
  __shared__ int  len_s2[8];
  __shared__ float wins2[8], wine2[8], winl2[8];

  for (int idx=tid; idx<8*T; idx+=512){ int r=idx/T, t=idx-r*T; tok_s2[r][t]=tokp[(row0+r)*T+t]; }
  if (tid < 8){
    int b = row0 + tid; len_s2[tid] = lenp[b];
    if (isCtx){ float s=(float)sstart[b], a=(float)alen[b];
      wins2[tid]=s; wine2[tid]=s+a-1.0f; winl2[tid]=(float)LCC - a; }
  }
  for (int idx=tid; idx<2400; idx+=512){ int r=idx/300, d=idx-r*300; hb[0][r][d]=0.f; }
  __syncthreads();
  int maxl=0;
  #pragma unroll
  for (int r=0;r<8;r++) maxl = max(maxl, len_s2[r]);

  const int n0=tid, n1=tid+512, n2=tid+1024;
  const bool has3 = tid<176;
  float b0=bias[n0], b1=bias[n1], b2=has3?bias[n2]:0.f;
  float creg[5];
  #pragma unroll
  for (int s=0;s<5;s++) creg[s]=0.f;
  int cur=0;

  for (int t=0; t<maxl; ++t){
    for (int idx=tid; idx<2400; idx+=512){
      int r=idx/300, d=idx-r*300;
      int L=len_s2[r];
      int ts = bwd ? ((t<L)?(L-1-t):t) : t;
      xb[r][d] = embed[(size_t)tok_s2[r][ts]*300 + d];
    }
    __syncthreads();

    float a0[8], a1[8], a2[8];
    #pragma unroll
    for (int r=0;r<8;r++){ a0[r]=b0; a1[r]=b1; a2[r]=b2; }
    kloop8(xb, Wi, a0, a1, a2, n0, n1, n2, has3);
    kloop8(hb[cur], Wh, a0, a1, a2, n0, n1, n2, has3);

    #pragma unroll
    for (int r=0;r<8;r++){ gsf[r][n0]=a0[r]; gsf[r][n1]=a1[r]; if(has3) gsf[r][n2]=a2[r]; }
    __syncthreads();

    #pragma unroll
    for (int s=0;s<5;s++){
      int idx = tid + s*512;
      if (idx < 2400){
        int r = idx/300, j = idx - r*300;
        int L = len_s2[r];
        if (t < L){
          float gi=gsf[r][j], gf=gsf[r][300+j], gg=gsf[r][600+j], go=gsf[r][900+j];
          float cn = sigf(gf)*creg[s] + sigf(gi)*tanhf(gg);
          float hn = sigf(go)*tanhf(cn);
          creg[s]=cn;
          hb[cur^1][r][j]=hn;
          int tpos = bwd ? (L-1-t) : t;
          float wgt = 1.0f;
          if (isCtx){
            float jf=(float)tpos, s_=wins2[r], e_=wine2[r], sl=winl2[r];
            wgt = (jf<s_)?(1.0f-(s_-jf)/sl):((jf<=e_)?0.0f:(1.0f-(jf-e_)/sl));
          }
          outb[((size_t)(row0+r)*T + tpos)*(size_t)D2 + coloff + j] = hn*wgt;
        }
      }
    }
    cur ^= 1;
  }
}

// ---------------- pooling ----------------
__global__ void k_pool(const float* __restrict__ ctx_out, const float* __restrict__ asp_out,
                       const int* __restrict__ clen, const int* __restrict__ alen,
                       float* __restrict__ ctx_pool, float* __restrict__ asp_pool){
  const int b=blockIdx.x; const int tid=threadIdx.x;
  for (int d=tid; d<D2; d+=blockDim.x){
    float s=0.f;
    for (int t=0;t<LCC;t++) s+=ctx_out[((size_t)b*LCC+t)*D2+d];
    ctx_pool[(size_t)b*D2+d]=s/(float)clen[b];
    float s2=0.f;
    for (int t=0;t<LAA;t++) s2+=asp_out[((size_t)b*LAA+t)*D2+d];
    asp_pool[(size_t)b*D2+d]=s2/(float)alen[b];
  }
}

// ---------------- v1/v2 matvecs ----------------
__global__ void k_v1v2(const float* __restrict__ w_a2c, const float* __restrict__ w_c2a,
                       const float* __restrict__ ctx_pool, const float* __restrict__ asp_pool,
                       float* __restrict__ v1, float* __restrict__ v2){
  const int b=blockIdx.x; const int tid=threadIdx.x;
  __shared__ __align__(16) float ap[600];
  __shared__ __align__(16) float cp[600];
  for (int d=tid;d<600;d+=256){ ap[d]=asp_pool[(size_t)b*D2+d]; cp[d]=ctx_pool[(size_t)b*D2+d]; }
  __syncthreads();
  for (int d=tid;d<600;d+=256){
    const float4* ra=(const float4*)(w_a2c+(size_t)d*600);
    const float4* rc=(const float4*)(w_c2a+(size_t)d*600);
    float s1=0.f,s2=0.f;
    for (int e4=0;e4<150;e4++){
      float4 wa=ra[e4], wc=rc[e4];
      const float4 av=*(const float4*)&ap[4*e4];
      const float4 cv=*(const float4*)&cp[4*e4];
      s1 = fmaf(wa.w,av.w,fmaf(wa.z,av.z,fmaf(wa.y,av.y,fmaf(wa.x,av.x,s1))));
      s2 = fmaf(wc.w,cv.w,fmaf(wc.z,cv.z,fmaf(wc.y,cv.y,fmaf(wc.x,cv.x,s2))));
    }
    v1[(size_t)b*D2+d]=s1; v2[(size_t)b*D2+d]=s2;
  }
}

// ---------------- fused attention + head ----------------
__launch_bounds__(256,2)
__global__ void k_attn(const float* __restrict__ ctx_out, const float* __restrict__ asp_out,
                       const float* __restrict__ v1, const float* __restrict__ v2,
                       const float* __restrict__ w_u, const float* __restrict__ dW,
                       const float* __restrict__ db, float* __restrict__ out)
{
  const int b = blockIdx.x;
  const int tid = threadIdx.x;
  const int wv = tid>>6, lane = tid&63;

  __shared__ float asp[16][600];
  __shared__ float w1s[600], w3s[600], v1s[600], v2s[600];
  __shared__ float u2s[16], m2w[4][16];
  __shared__ float m1s[128], s1s[128];
  __shared__ float alph[128], a1s[128];
  __shared__ float bet[16], a2s[16], m2f[16], s2s[16];
  __shared__ float red[256];
  __shared__ float feat[2400];

  for (int idx=tid; idx<16*600; idx+=256){
    int j=idx/600, d=idx-j*600;
    asp[j][d]=asp_out[((size_t)b*LAA+j)*D2+d];
  }
  for (int d=tid; d<600; d+=256){
    w1s[d]=w_u[d]; w3s[d]=w_u[1200+d];
    v1s[d]=v1[(size_t)b*D2+d]; v2s[d]=v2[(size_t)b*D2+d];
  }
  if (tid<64) m2w[tid>>4][tid&15] = -1e30f;
  __syncthreads();
  if (tid<16){
    float s=0.f;
    for (int d=0;d<600;d++) s += asp[tid][d]*w_u[600+d];
    u2s[tid]=s;
  }
  __syncthreads();

  float m2p[16];
  #pragma unroll
  for (int j=0;j<16;j++) m2p[j]=-1e30f;

  for (int i=wv; i<LCC; i+=4){
    const float* crow = ctx_out + ((size_t)b*LCC+i)*D2;
    float u1p=0.f, s1p=0.f, accj[16];
    #pragma unroll
    for (int j=0;j<16;j++) accj[j]=0.f;
    for (int m=0;m<10;m++){
      int d = lane + m*64;
      if (d<600){
        float v = crow[d];
        u1p = fmaf(v,w1s[d],u1p);
        s1p = fmaf(v,v1s[d],s1p);
        float cw = v*w3s[d];
        #pragma unroll
        for (int j=0;j<16;j++) accj[j] = fmaf(cw,asp[j][d],accj[j]);
      }
    }
    #pragma unroll
    for (int off=32; off>0; off>>=1){
      u1p += __shfl_xor(u1p,off);
      s1p += __shfl_xor(s1p,off);
      #pragma unroll
      for (int j=0;j<16;j++) accj[j] += __shfl_xor(accj[j],off);
    }
    float mj=-1e30f;
    #pragma unroll
    for (int j=0;j<16;j++){
      float a = u2s[j]+accj[j];
      mj = fmaxf(mj,a);
      m2p[j] = fmaxf(m2p[j], u1p+accj[j]);
    }
    if (lane==0){ m1s[i]=u1p+mj; s1s[i]=s1p; }
  }
  if (lane<16) m2w[wv][lane]=m2p[lane];
  __syncthreads();

  {
    float x1 = (tid<128)? m1s[tid] : -1e30f;
    red[tid]=x1; __syncthreads();
    for (int s=128;s>0;s>>=1){ if (tid<s) red[tid]=fmaxf(red[tid],red[tid+s]); __syncthreads(); }
    float M1=red[0]; __syncthreads();
    float e1=(tid<128)?expf(x1-M1):0.f;
    red[tid]=e1; __syncthreads();
    for (int s=128;s>0;s>>=1){ if (tid<s) red[tid]+=red[tid+s]; __syncthreads(); }
    float S1=red[0]; __syncthreads();
    if (tid<128) alph[tid]=e1/S1;

    float x2 = (tid<128)? s1s[tid] : -1e30f;
    red[tid]=x2; __syncthreads();
    for (int s=128;s>0;s>>=1){ if (tid<s) red[tid]=fmaxf(red[tid],red[tid+s]); __syncthreads(); }
    float M2=red[0]; __syncthreads();
    float e2=(tid<128)?expf(x2-M2):0.f;
    red[tid]=e2; __syncthreads();
    for (int s=128;s>0;s>>=1){ if (tid<s) red[tid]+=red[tid+s]; __syncthreads(); }
    float S2=red[0]; __syncthreads();
    if (tid<128) a1s[tid]=e2/S2;
  }

  if (tid<16){
    float m=-1e30f;
    #pragma unroll
    for (int w=0;w<4;w++) m=fmaxf(m,m2w[w][tid]);
    m2f[tid]=u2s[tid]+m;
    float s=0.f;
    for (int d=0;d<600;d++) s = fmaf(asp[tid][d],v2s[d],s);
    s2s[tid]=s;
  }
  __syncthreads();
  if (tid==0){
    float M=-1e30f,S=0.f;
    for (int j=0;j<16;j++) M=fmaxf(M,m2f[j]);
    for (int j=0;j<16;j++){ float e=expf(m2f[j]-M); bet[j]=e; S+=e; }
    for (int j=0;j<16;j++) bet[j]/=S;
    M=-1e30f;S=0.f;
    for (int j=0;j<16;j++) M=fmaxf(M,s2s[j]);
    for (int j=0;j<16;j++){ float e=expf(s2s[j]-M); a2s[j]=e; S+=e; }
    for (int j=0;j<16;j++) a2s[j]/=S;
  }
  __syncthreads();

  {
    const bool has2 = (tid<88);
    float fa0=0,fa1=0,fa2=0, ca0=0,ca1=0,ca2=0;
    for (int i=0;i<LCC;i++){
      float al=alph[i], aa=a1s[i];
      const float* crow = ctx_out + ((size_t)b*LCC+i)*D2;
      float x0=crow[tid];      fa0=fmaf(al,x0,fa0); ca0=fmaf(aa,x0,ca0);
      float x1=crow[tid+256];  fa1=fmaf(al,x1,fa1); ca1=fmaf(aa,x1,ca1);
      if (has2){ float x2=crow[tid+512]; fa2=fmaf(al,x2,fa2); ca2=fmaf(aa,x2,ca2); }
    }
    feat[tid]=ca0;           feat[600+tid]=fa0;
    feat[tid+256]=ca1;       feat[600+tid+256]=fa1;
    if (has2){ feat[tid+512]=ca2; feat[600+tid+512]=fa2; }

    float fc0=0,fc1=0,fc2=0, cc0=0,cc1=0,cc2=0;
    for (int j=0;j<16;j++){
      float be=bet[j], a2=a2s[j];
      float x0=asp[j][tid];      fc0=fmaf(be,x0,fc0); cc0=fmaf(a2,x0,cc0);
      float x1=asp[j][tid+256];  fc1=fmaf(be,x1,fc1); cc1=fmaf(a2,x1,cc1);
      if (has2){ float x2=asp[j][tid+512]; fc2=fmaf(be,x2,fc2); cc2=fmaf(a2,x2,cc2); }
    }
    feat[1200+tid]=fc0;        feat[1800+tid]=cc0;
    feat[1200+tid+256]=fc1;    feat[1800+tid+256]=cc1;
    if (has2){ feat[1200+tid+512]=fc2; feat[1800+tid+512]=cc2; }
  }
  __syncthreads();

  {
    float p0=0,p1=0,p2=0;
    for (int e=tid;e<2400;e+=256){
      float f=feat[e];
      p0=fmaf(f,dW[e],p0); p1=fmaf(f,dW[2400+e],p1); p2=fmaf(f,dW[4800+e],p2);
    }
    red[tid]=p0; __syncthreads();
    for (int s=128;s>0;s>>=1){ if (tid<s) red[tid]+=red[tid+s]; __syncthreads(); }
    if (tid==0) out[b*3+0]=red[0]+db[0];
    __syncthreads();
    red[tid]=p1; __syncthreads();
    for (int s=128;s>0;s>>=1){ if (tid<s) red[tid]+=red[tid+s]; __syncthreads(); }
    if (tid==0) out[b*3+1]=red[0]+db[1];
    __syncthreads();
    red[tid]=p2; __syncthreads();
    for (int s=128;s>0;s>>=1){ if (tid<s) red[tid]+=red[tid+s]; __syncthreads(); }
    if (tid==0) out[b*3+2]=red[0]+db[2];
  }
}

extern "C" void kernel_launch(void* const* d_in, const int* in_sizes, int n_in,
                              void* d_out, int out_size, void* d_ws, size_t ws_size,
                              hipStream_t stream) {
  const int*   traw =(const int*)d_in[0];
  const int*   tasp =(const int*)d_in[1];
  const int*   tleft=(const int*)d_in[2];
  const float* embed=(const float*)d_in[3];
  const float* cWif=(const float*)d_in[4];
  const float* cWhf=(const float*)d_in[5];
  const float* cbf =(const float*)d_in[6];
  const float* cWib=(const float*)d_in[7];
  const float* cWhb=(const float*)d_in[8];
  const float* cbb =(const float*)d_in[9];
  const float* aWif=(const float*)d_in[10];
  const float* aWhf=(const float*)d_in[11];
  const float* abf =(const float*)d_in[12];
  const float* aWib=(const float*)d_in[13];
  const float* aWhb=(const float*)d_in[14];
  const float* abb =(const float*)d_in[15];
  const float* w_u =(const float*)d_in[16];
  const float* w_a2c=(const float*)d_in[17];
  const float* w_c2a=(const float*)d_in[18];
  const float* dW  =(const float*)d_in[19];
  const float* db  =(const float*)d_in[20];
  float* out = (float*)d_out;

  char* w = (char*)d_ws;
  size_t o = 0;
  float* ctx_out  = (float*)(w+o); o += (size_t)BB*LCC*D2*4;          // 157,286,400
  float* asp_out  = (float*)(w+o); o += (size_t)BB*LAA*D2*4;          //  19,660,800
  char*  Wshare   = (char*)(w+o);  o += (size_t)13107200;             // Wfrag (13.1MB) | WT4 alias (11.5MB)
  float* ctx_pool = (float*)(w+o); o += (size_t)BB*D2*4;
  float* asp_pool = (float*)(w+o); o += (size_t)BB*D2*4;
  float* v1       = (float*)(w+o); o += (size_t)BB*D2*4;
  float* v2       = (float*)(w+o); o += (size_t)BB*D2*4;
  int*   clen     = (int*)(w+o);   o += (size_t)BB*4;
  int*   alen_    = (int*)(w+o);   o += (size_t)BB*4;
  int*   sstart   = (int*)(w+o);   o += (size_t)BB*4;
  size_t need_base = o;
  float* bias_p   = (float*)(w+o); o += (size_t)4*NP*4;               // 20,480
  short* xg_all   = (short*)(w+o); o += (size_t)128*16*TC*NP*2;       // 20,971,520
  const int use_mfma = (ws_size >= o) ? 1 : 0;
  (void)need_base;

  hipMemsetAsync(ctx_out, 0, (size_t)BB*LCC*D2*4 + (size_t)BB*LAA*D2*4, stream);

  k_lengths<<<4,128,0,stream>>>(traw,tasp,tleft,clen,alen_,sstart);

  if (use_mfma){
    k_prep_frag<<<dim3(NT*KT,8),64,0,stream>>>(cWif,cWhf,cWib,cWhb,aWif,aWhf,aWib,aWhb,(short*)Wshare);
    k_prep_bias<<<dim3(4,5),256,0,stream>>>(cbf,cbb,abf,abb,bias_p);
    k_rec_mfma<<<128,512,0,stream>>>(traw,tasp,embed,(const short*)Wshare,bias_p,
                                     clen,alen_,sstart,xg_all,ctx_out,asp_out);
  } else {
    k_prep_f32<<<dim3(352,1,8),256,0,stream>>>(cWif,cWhf,cWib,cWhb,aWif,aWhf,aWib,aWhb,(float*)Wshare);
    k_rec_f32<<<256,512,0,stream>>>(traw,tasp,embed,(const float*)Wshare,
                                    cbf,cbb,abf,abb,clen,alen_,sstart,ctx_out,asp_out);
  }

  k_pool<<<512,256,0,stream>>>(ctx_out,asp_out,clen,alen_,ctx_pool,asp_pool);
  k_v1v2<<<512,256,0,stream>>>(w_a2c,w_c2a,ctx_pool,asp_pool,v1,v2);
  k_attn<<<512,256,0,stream>>>(ctx_out,asp_out,v1,v2,w_u,dW,db,out);
}

// Round 4
// 7373.486 us; speedup vs baseline: 1.8594x; 1.8594x over previous
//
#include <hip/hip_runtime.h>
#include <math.h>

#define BB 512
#define LCC 128
#define LAA 16
#define D2 600
#define NT 80
#define KT 10
#define NP 1280
#define F1 409600            // shorts per fragment matrix (0.8 MB)

static const size_t J0 = (size_t)512*128*1280;   // ctx xg elems per dir
static const size_t J1 = (size_t)512*16*1280;    // asp xg elems per dir

typedef __attribute__((ext_vector_type(8))) short bf16x8;
typedef __attribute__((ext_vector_type(4))) float f32x4;

__device__ __forceinline__ float sigf(float x){ return 1.0f/(1.0f+expf(-x)); }
__device__ __forceinline__ unsigned short f2bf(float f){
  unsigned u = __float_as_uint(f);
  unsigned r = (u + 0x7FFFu + ((u>>16)&1u)) >> 16;
  return (unsigned short)r;
}
__device__ __forceinline__ float bf2f(unsigned short h){ return __uint_as_float(((unsigned)h)<<16); }

// ---------------- lengths ----------------
__global__ void k_lengths(const int* __restrict__ traw, const int* __restrict__ tasp,
                          const int* __restrict__ tleft,
                          int* __restrict__ clen, int* __restrict__ alen, int* __restrict__ sstart){
  int b = blockIdx.x*blockDim.x + threadIdx.x;
  if (b >= BB) return;
  int c=0,a=0,l=0;
  for (int t=0;t<LCC;t++) c += (traw[b*LCC+t]!=0);
  for (int t=0;t<LAA;t++) a += (tasp[b*LAA+t]!=0);
  for (int t=0;t<LCC;t++) l += (tleft[b*LCC+t]!=0);
  clen[b]=c; alen[b]=a; sstart[b]=l;
}

// ---------------- MFMA weight fragments ----------------
// tasks 0..7: hi(bf16) of {cWif,cWhf,cWib,cWhb,aWif,aWhf,aWib,aWhb}
// tasks 8..11: lo residual of Wh for job 0..3 (mats 1,3,5,7)
// layout per matrix: [nt<80][kt<10][lane<64][e<8] bf16
// n' = nt*16+(lane&15); orig n = 300*(n'&3) + (n'>>2); k = kt*32+4*(lane>>4)+(e&3)+16*(e>>2)
__global__ void k_prep_frag(const float* __restrict__ cWif,const float* __restrict__ cWhf,
                            const float* __restrict__ cWib,const float* __restrict__ cWhb,
                            const float* __restrict__ aWif,const float* __restrict__ aWhf,
                            const float* __restrict__ aWib,const float* __restrict__ aWhb,
                            short* __restrict__ Wfrag){
  const int task = blockIdx.y;
  const float* mats[8] = {cWif,cWhf,cWib,cWhb,aWif,aWhf,aWib,aWhb};
  const float* W; int lo;
  if (task < 8){ W = mats[task]; lo = 0; }
  else { W = mats[(task-8)*2+1]; lo = 1; }
  short* dst = Wfrag + (size_t)task*F1;
  const int nt = blockIdx.x/KT, kt = blockIdx.x%KT;
  const int lane = threadIdx.x;
  const int np = nt*16 + (lane&15);
  const int g  = lane>>4;
  const int n  = (np<1200) ? 300*(np&3) + (np>>2) : -1;
  size_t bi = (((size_t)nt*KT + kt)*64 + lane)*8;
  #pragma unroll
  for (int e=0;e<8;++e){
    int k = kt*32 + 4*g + (e&3) + 16*(e>>2);
    float v = (n>=0 && k<300) ? W[(size_t)n*300+k] : 0.f;
    unsigned short hi = f2bf(v);
    short outv;
    if (!lo) outv = (short)hi;
    else     outv = (short)f2bf(v - bf2f(hi));
    dst[bi+e] = outv;
  }
}

// bias permuted to n' order, padded to 1280
__global__ void k_prep_bias(const float* __restrict__ cbf,const float* __restrict__ cbb,
                            const float* __restrict__ abf,const float* __restrict__ abb,
                            float* __restrict__ bias_p){
  int j = blockIdx.x;
  int np = blockIdx.y*256 + threadIdx.x;
  if (np>=NP) return;
  const float* b = (j==0)?cbf:(j==1)?cbb:(j==2)?abf:abb;
  bias_p[j*NP+np] = (np<1200) ? b[300*(np&3)+(np>>2)] : 0.f;
}

// ---------------- xg precompute (all 4 jobs): xg = x.Wi^T + b, bf16 ----------------
// grid 4608: [0,2048) ctx-f, [2048,4096) ctx-b (b=rloc>>2, tchunk=rloc&3, 32 t-rows),
//            [4096,4352) asp-f, [4352,4608) asp-b (2 samples x 16 t-rows)
__launch_bounds__(512,1)
__global__ void k_xg(const int* __restrict__ traw, const int* __restrict__ tasp,
                     const float* __restrict__ embed,
                     const short* __restrict__ Wfrag, const float* __restrict__ bias_p,
                     const int* __restrict__ clen, const int* __restrict__ alen,
                     short* __restrict__ xg)
{
  const int bid = blockIdx.x, tid = threadIdx.x;
  const int lane = tid&63, wv = tid>>6;
  int job, rloc;
  if (bid < 4096){ job = bid>>11; rloc = bid & 2047; }
  else { int a = bid-4096; job = 2+(a>>8); rloc = a & 255; }
  const int isCtx = (job<2), bwd = (job&1);
  short* xgj = isCtx ? (xg + (size_t)job*J0) : (xg + 2*J0 + (size_t)(job-2)*J1);

  __shared__ int tokL[32];
  __shared__ unsigned rowoff[32];
  __shared__ float biasL[NP];
  __shared__ __align__(16) short stgx[2][KT][64][8];

  if (tid < 32){
    int m = tid, tok, off;
    if (isCtx){
      int b = rloc>>2, t = (rloc&3)*32 + m;
      int L = clen[b];
      int pos = bwd ? ((t<L)? L-1-t : t) : t;
      tok = traw[b*LCC+pos];
      off = b*LCC + t;
    } else {
      int s = rloc*2 + (m>>4), tt = m&15;
      int L = alen[s];
      int pos = bwd ? ((tt<L)? L-1-tt : tt) : tt;
      tok = tasp[s*LAA+pos];
      off = s*LAA + tt;
    }
    tokL[m] = tok; rowoff[m] = (unsigned)off*NP;
  }
  for (int i=tid;i<NP;i+=512) biasL[i]=bias_p[job*NP+i];
  __syncthreads();

  // stage 32 A-rows as 2 fragments x 10 kt
  for (int it=tid; it<2*KT*64; it+=512){
    int l = it&63, kt = (it>>6)%KT, mf = it/(64*KT);
    int m = mf*16 + (l&15), lg2 = l>>4;
    const float* erow = embed + (size_t)tokL[m]*300;
    int k0 = kt*32 + 4*lg2;
    float4 pa = {0.f,0.f,0.f,0.f}, pb = {0.f,0.f,0.f,0.f};
    if (k0+3  < 300) pa = *(const float4*)(erow + k0);
    if (k0+19 < 300) pb = *(const float4*)(erow + k0 + 16);
    bf16x8 pk;
    pk[0]=(short)f2bf(pa.x); pk[1]=(short)f2bf(pa.y); pk[2]=(short)f2bf(pa.z); pk[3]=(short)f2bf(pa.w);
    pk[4]=(short)f2bf(pb.x); pk[5]=(short)f2bf(pb.y); pk[6]=(short)f2bf(pb.z); pk[7]=(short)f2bf(pb.w);
    *(bf16x8*)&stgx[mf][kt][l][0] = pk;
  }
  __syncthreads();

  const int nt0 = wv*10;
  const int col = lane&15, lg = lane>>4;
  const bf16x8* Wi = (const bf16x8*)(Wfrag + (size_t)(2*job)*F1);

  f32x4 acc[2][10];
  #pragma unroll
  for (int m=0;m<2;++m)
    #pragma unroll
    for (int i=0;i<10;++i) acc[m][i] = (f32x4){0.f,0.f,0.f,0.f};

  for (int kt=0; kt<KT; ++kt){
    bf16x8 a0 = *(const bf16x8*)&stgx[0][kt][lane][0];
    bf16x8 a1 = *(const bf16x8*)&stgx[1][kt][lane][0];
    #pragma unroll
    for (int ntl=0; ntl<10; ++ntl){
      bf16x8 bb = Wi[(size_t)((nt0+ntl)*KT + kt)*64 + lane];
      acc[0][ntl] = __builtin_amdgcn_mfma_f32_16x16x32_bf16(a0, bb, acc[0][ntl], 0,0,0);
      acc[1][ntl] = __builtin_amdgcn_mfma_f32_16x16x32_bf16(a1, bb, acc[1][ntl], 0,0,0);
    }
  }
  #pragma unroll
  for (int ntl=0; ntl<10; ++ntl){
    int np = (nt0+ntl)*16 + col;
    float bv = biasL[np];
    #pragma unroll
    for (int mf=0; mf<2; ++mf){
      #pragma unroll
      for (int q=0;q<4;++q){
        int m = mf*16 + lg*4 + q;                // C/D: col=lane&15, row=(lane>>4)*4+q
        short v = (short)f2bf(acc[mf][ntl][q] + bv);
        __builtin_nontemporal_store(v, xgj + (size_t)rowoff[m] + np);
      }
    }
  }
}

// ---------------- Wh-only MFMA recurrence ----------------
// 128 blocks x 512. Each XCD hosts blocks of both ctx jobs (Wh hi+lo 2x1.6MB L2-resident).
// 16 rows/block; per step: split-bf16 MFMA Wh.h -> per-wave LDS D-tile transpose -> gates (+xg nt-load)
// -> h write to hfrag dbuf. ONE barrier per step.
__launch_bounds__(512,1)
__global__ void k_rec_mfma(const short* __restrict__ Wfrag, const short* __restrict__ xg,
                           const int* __restrict__ clen, const int* __restrict__ alen,
                           const int* __restrict__ sstart,
                           float* __restrict__ ctx_out, float* __restrict__ asp_out)
{
  const int tid = threadIdx.x, lane = tid&63, wv = tid>>6;
  const int bid = blockIdx.x;
  const int q8 = bid & 7, s8 = bid >> 3;
  int job, wj;
  if (s8 < 4){ job = 0; wj = s8*8 + q8; }
  else if (s8 < 8){ job = 1; wj = (s8-4)*8 + q8; }
  else if (s8 < 12){ job = 2; wj = (s8-8)*8 + q8; }
  else { job = 3; wj = (s8-12)*8 + q8; }
  const int isCtx = (job<2), bwd = (job&1);
  const int T = isCtx ? LCC : LAA;
  const int row0 = wj*16;
  const int* lenp = isCtx ? clen : alen;
  float* outb = isCtx ? ctx_out : asp_out;
  const int coloff = bwd ? 300 : 0;
  const bf16x8* WhHi = (const bf16x8*)(Wfrag + (size_t)(2*job+1)*F1);
  const bf16x8* WhLo = (const bf16x8*)(Wfrag + (size_t)(8+job)*F1);
  const short* xgj = isCtx ? (xg + (size_t)job*J0) : (xg + 2*J0 + (size_t)(job-2)*J1);

  __shared__ __align__(16) short hfrag[2][KT][64][8];
  __shared__ __align__(16) float dtile[8][256];
  __shared__ int len_s[16];

  if (tid < 16) len_s[tid] = lenp[row0+tid];
  for (int i=tid; i<2*KT*64*8; i+=512) ((short*)hfrag)[i]=0;
  __syncthreads();
  int maxl=0;
  #pragma unroll
  for (int rr=0;rr<16;++rr) maxl = max(maxl, len_s[rr]);

  const int r = lane&15, jl = lane>>4;
  const int L = len_s[r];
  float win_s=0.f, win_e=0.f, win_sl=1.f;
  if (isCtx){
    float s=(float)sstart[row0+r], a=(float)alen[row0+r];
    win_s=s; win_e=s+a-1.0f; win_sl=(float)LCC - a;
  }
  const size_t xrow = ((size_t)(row0+r)*T)*NP;
  const size_t orow = ((size_t)(row0+r)*T)*(size_t)D2 + coloff;
  const int nt0 = wv*10;
  float cst[10];
  #pragma unroll
  for (int i=0;i<10;++i) cst[i]=0.f;
  int cur=0;

  for (int t=0; t<maxl; ++t){
    bf16x8 af[10];
    #pragma unroll
    for (int kt=0;kt<KT;++kt) af[kt] = *(const bf16x8*)&hfrag[cur][kt][lane][0];

    f32x4 ga[10];
    #pragma unroll
    for (int i=0;i<10;++i) ga[i] = (f32x4){0.f,0.f,0.f,0.f};

    #pragma unroll
    for (int kt=0;kt<KT;++kt){
      #pragma unroll
      for (int ntl=0;ntl<10;++ntl){
        bf16x8 bb = WhHi[(size_t)((nt0+ntl)*KT + kt)*64 + lane];
        ga[ntl] = __builtin_amdgcn_mfma_f32_16x16x32_bf16(af[kt], bb, ga[ntl], 0,0,0);
      }
    }
    #pragma unroll
    for (int kt=0;kt<KT;++kt){
      #pragma unroll
      for (int ntl=0;ntl<10;++ntl){
        bf16x8 bb = WhLo[(size_t)((nt0+ntl)*KT + kt)*64 + lane];
        ga[ntl] = __builtin_amdgcn_mfma_f32_16x16x32_bf16(af[kt], bb, ga[ntl], 0,0,0);
      }
    }

    const int nxt = cur^1;
    #pragma unroll
    for (int ntl=0;ntl<10;++ntl){
      // per-wave private D-tile: write C/D layout, read back per (r,j)
      #pragma unroll
      for (int q=0;q<4;++q)
        dtile[wv][(jl*4+q)*16 + r] = ga[ntl][q];   // (lane>>4)=row-group, (lane&15)=col
      float4 g4 = *(const float4*)&dtile[wv][r*16 + jl*4];
      int j = (nt0+ntl)*4 + jl;
      unsigned long long raw = __builtin_nontemporal_load(
          (const unsigned long long*)(xgj + xrow + (size_t)t*NP + 4*j));
      if (t < L){
        float gi = g4.x + bf2f((unsigned short)( raw        & 0xFFFF));
        float gf = g4.y + bf2f((unsigned short)((raw >> 16) & 0xFFFF));
        float gg = g4.z + bf2f((unsigned short)((raw >> 32) & 0xFFFF));
        float go = g4.w + bf2f((unsigned short)((raw >> 48) & 0xFFFF));
        float cn = sigf(gf)*cst[ntl] + sigf(gi)*tanhf(gg);
        float hn = sigf(go)*tanhf(cn);
        cst[ntl] = cn;
        int kt2 = j>>5, kk = j&31;
        int g2 = (kk&15)>>2, e = (kk&3) + 4*(kk>>4);
        hfrag[nxt][kt2][g2*16 + r][e] = (short)f2bf(hn);
        int tpos = bwd ? (L-1-t) : t;
        float wgt = 1.0f;
        if (isCtx){
          float jf=(float)tpos;
          wgt = (jf<win_s)?(1.0f-(win_s-jf)/win_sl):((jf<=win_e)?0.0f:(1.0f-(jf-win_e)/win_sl));
        }
        __builtin_nontemporal_store(hn*wgt, outb + orow + (size_t)tpos*D2 + j);
      }
    }
    __syncthreads();
    cur = nxt;
  }
}

// ================= fallback f32 path (round-2, verified) =================
__global__ void k_prep_f32(const float* __restrict__ cWif,const float* __restrict__ cWhf,
                           const float* __restrict__ cWib,const float* __restrict__ cWhb,
                           const float* __restrict__ aWif,const float* __restrict__ aWhf,
                           const float* __restrict__ aWib,const float* __restrict__ aWhb,
                           float* __restrict__ WT4){
  const int m = blockIdx.z;
  const float* src;
  switch(m){
    case 0: src=cWif; break; case 1: src=cWhf; break;
    case 2: src=cWib; break; case 3: src=cWhb; break;
    case 4: src=aWif; break; case 5: src=aWhf; break;
    case 6: src=aWib; break; default: src=aWhb; break;
  }
  int rem = blockIdx.x*blockDim.x + threadIdx.x;
  if (rem >= 90000) return;
  int kq = rem/1200, n = rem - kq*1200;
  float4 v = *(const float4*)(src + (size_t)n*300 + kq*4);
  ((float4*)WT4)[(size_t)m*90000 + rem] = v;
}

__device__ __forceinline__ void kloop8(const float (*__restrict__ src)[300],
                                       const float* __restrict__ W,
                                       float* a0, float* a1, float* a2,
                                       int n0, int n1, int n2, bool has3){
  const float4* Wp = (const float4*)W;
  for (int kq=0; kq<75; ++kq){
    float4 w0 = Wp[n0];
    float4 w1 = Wp[n1];
    #pragma unroll
    for (int r=0;r<8;r++){
      float4 h4 = *(const float4*)&src[r][4*kq];
      a0[r]=fmaf(w0.w,h4.w,fmaf(w0.z,h4.z,fmaf(w0.y,h4.y,fmaf(w0.x,h4.x,a0[r]))));
      a1[r]=fmaf(w1.w,h4.w,fmaf(w1.z,h4.z,fmaf(w1.y,h4.y,fmaf(w1.x,h4.x,a1[r]))));
    }
    if (has3){
      float4 w2 = Wp[n2];
      #pragma unroll
      for (int r=0;r<8;r++){
        float4 h4 = *(const float4*)&src[r][4*kq];
        a2[r]=fmaf(w2.w,h4.w,fmaf(w2.z,h4.z,fmaf(w2.y,h4.y,fmaf(w2.x,h4.x,a2[r]))));
      }
    }
    Wp += 1200;
  }
}

__launch_bounds__(512,1)
__global__ void k_rec_f32(const int* __restrict__ traw, const int* __restrict__ tasp,
                          const float* __restrict__ embed,
                          const float* __restrict__ WT4,
                          const float* __restrict__ cbf, const float* __restrict__ cbb,
                          const float* __restrict__ abf, const float* __restrict__ abb,
                          const int* __restrict__ clen, const int* __restrict__ alen,
                          const int* __restrict__ sstart,
                          float* __restrict__ ctx_out, float* __restrict__ asp_out)
{
  const int tid = threadIdx.x;
  const int job = blockIdx.x & 3;
  const int sub = blockIdx.x >> 2;
  const int row0 = sub*8;
  const int isCtx = (job < 2), bwd = (job & 1);
  const int T = isCtx ? LCC : LAA;
  const int* lenp = isCtx ? clen : alen;
  const int* tokp = isCtx ? traw : tasp;
  const float* Wi = WT4 + (size_t)(job*2)*360000;
  const float* Wh = Wi + 360000;
  const float* bias = (job==0)?cbf:(job==1)?cbb:(job==2)?abf:abb;
  float* outb = isCtx ? ctx_out : asp_out;
  const int coloff = bwd ? 300 : 0;

  __shared__ __align__(16) float hb[2][8][300];
  __shared__ __align__(16) float xb[8][300];
  __shared__ float gsf[8][1200];
  __shared__ int  tok_s2[8][LCC];
  __shared__ int  len_s2[8];
  __shared__ float wins2[8], wine2[8], winl2[8];

  for (int idx=tid; idx<8*T; idx+=512){ int r=idx/T, t=idx-r*T; tok_s2[r][t]=tokp[(row0+r)*T+t]; }
  if (tid < 8){
    int b = row0 + tid; len_s2[tid] = lenp[b];
    if (isCtx){ float s=(float)sstart[b], a=(float)alen[b];
      wins2[tid]=s; wine2[tid]=s+a-1.0f; winl2[tid]=(float)LCC - a; }
  }
  for (int idx=tid; idx<2400; idx+=512){ int r=idx/300, d=idx-r*300; hb[0][r][d]=0.f; }
  __syncthreads();
  int maxl=0;
  #pragma unroll
  for (int r=0;r<8;r++) maxl = max(maxl, len_s2[r]);

  const int n0=tid, n1=tid+512, n2=tid+1024;
  const bool has3 = tid<176;
  float b0=bias[n0], b1=bias[n1], b2=has3?bias[n2]:0.f;
  float creg[5];
  #pragma unroll
  for (int s=0;s<5;s++) creg[s]=0.f;
  int cur=0;

  for (int t=0; t<maxl; ++t){
    for (int idx=tid; idx<2400; idx+=512){
      int r=idx/300, d=idx-r*300;
      int Lr=len_s2[r];
      int ts = bwd ? ((t<Lr)?(Lr-1-t):t) : t;
      xb[r][d] = embed[(size_t)tok_s2[r][ts]*300 + d];
    }
    __syncthreads();

    float a0[8], a1[8], a2[8];
    #pragma unroll
    for (int r=0;r<8;r++){ a0[r]=b0; a1[r]=b1; a2[r]=b2; }
    kloop8(xb, Wi, a0, a1, a2, n0, n1, n2, has3);
    kloop8(hb[cur], Wh, a0, a1, a2, n0, n1, n2, has3);

    #pragma unroll
    for (int r=0;r<8;r++){ gsf[r][n0]=a0[r]; gsf[r][n1]=a1[r]; if(has3) gsf[r][n2]=a2[r]; }
    __syncthreads();

    #pragma unroll
    for (int s=0;s<5;s++){
      int idx = tid + s*512;
      if (idx < 2400){
        int r = idx/300, j = idx - r*300;
        int Lr = len_s2[r];
        if (t < Lr){
          float gi=gsf[r][j], gf=gsf[r][300+j], gg=gsf[r][600+j], go=gsf[r][900+j];
          float cn = sigf(gf)*creg[s] + sigf(gi)*tanhf(gg);
          float hn = sigf(go)*tanhf(cn);
          creg[s]=cn;
          hb[cur^1][r][j]=hn;
          int tpos = bwd ? (Lr-1-t) : t;
          float wgt = 1.0f;
          if (isCtx){
            float jf=(float)tpos, s_=wins2[r], e_=wine2[r], sl=winl2[r];
            wgt = (jf<s_)?(1.0f-(s_-jf)/sl):((jf<=e_)?0.0f:(1.0f-(jf-e_)/sl));
          }
          outb[((size_t)(row0+r)*T + tpos)*(size_t)D2 + coloff + j] = hn*wgt;
        }
      }
    }
    cur ^= 1;
  }
}

// ---------------- pooling ----------------
__global__ void k_pool(const float* __restrict__ ctx_out, const float* __restrict__ asp_out,
                       const int* __restrict__ clen, const int* __restrict__ alen,
                       float* __restrict__ ctx_pool, float* __restrict__ asp_pool){
  const int b=blockIdx.x; const int tid=threadIdx.x;
  for (int d=tid; d<D2; d+=blockDim.x){
    float s=0.f;
    for (int t=0;t<LCC;t++) s+=ctx_out[((size_t)b*LCC+t)*D2+d];
    ctx_pool[(size_t)b*D2+d]=s/(float)clen[b];
    float s2=0.f;
    for (int t=0;t<LAA;t++) s2+=asp_out[((size_t)b*LAA+t)*D2+d];
    asp_pool[(size_t)b*D2+d]=s2/(float)alen[b];
  }
}

// ---------------- v1/v2 matvecs ----------------
__global__ void k_v1v2(const float* __restrict__ w_a2c, const float* __restrict__ w_c2a,
                       const float* __restrict__ ctx_pool, const float* __restrict__ asp_pool,
                       float* __restrict__ v1, float* __restrict__ v2){
  const int b=blockIdx.x; const int tid=threadIdx.x;
  __shared__ __align__(16) float ap[600];
  __shared__ __align__(16) float cp[600];
  for (int d=tid;d<600;d+=256){ ap[d]=asp_pool[(size_t)b*D2+d]; cp[d]=ctx_pool[(size_t)b*D2+d]; }
  __syncthreads();
  for (int d=tid;d<600;d+=256){
    const float4* ra=(const float4*)(w_a2c+(size_t)d*600);
    const float4* rc=(const float4*)(w_c2a+(size_t)d*600);
    float s1=0.f,s2=0.f;
    for (int e4=0;e4<150;e4++){
      float4 wa=ra[e4], wc=rc[e4];
      const float4 av=*(const float4*)&ap[4*e4];
      const float4 cv=*(const float4*)&cp[4*e4];
      s1 = fmaf(wa.w,av.w,fmaf(wa.z,av.z,fmaf(wa.y,av.y,fmaf(wa.x,av.x,s1))));
      s2 = fmaf(wc.w,cv.w,fmaf(wc.z,cv.z,fmaf(wc.y,cv.y,fmaf(wc.x,cv.x,s2))));
    }
    v1[(size_t)b*D2+d]=s1; v2[(size_t)b*D2+d]=s2;
  }
}

// ---------------- fused attention + head ----------------
__launch_bounds__(256,2)
__global__ void k_attn(const float* __restrict__ ctx_out, const float* __restrict__ asp_out,
                       const float* __restrict__ v1, const float* __restrict__ v2,
                       const float* __restrict__ w_u, const float* __restrict__ dW,
                       const float* __restrict__ db, float* __restrict__ out)
{
  const int b = blockIdx.x;
  const int tid = threadIdx.x;
  const int wv = tid>>6, lane = tid&63;

  __shared__ float asp[16][600];
  __shared__ float w1s[600], w3s[600], v1s[600], v2s[600];
  __shared__ float u2s[16], m2w[4][16];
  __shared__ float m1s[128], s1s[128];
  __shared__ float alph[128], a1s[128];
  __shared__ float bet[16], a2s[16], m2f[16], s2s[16];
  __shared__ float red[256];
  __shared__ float feat[2400];

  for (int idx=tid; idx<16*600; idx+=256){
    int j=idx/600, d=idx-j*600;
    asp[j][d]=asp_out[((size_t)b*LAA+j)*D2+d];
  }
  for (int d=tid; d<600; d+=256){
    w1s[d]=w_u[d]; w3s[d]=w_u[1200+d];
    v1s[d]=v1[(size_t)b*D2+d]; v2s[d]=v2[(size_t)b*D2+d];
  }
  if (tid<64) m2w[tid>>4][tid&15] = -1e30f;
  __syncthreads();
  if (tid<16){
    float s=0.f;
    for (int d=0;d<600;d++) s += asp[tid][d]*w_u[600+d];
    u2s[tid]=s;
  }
  __syncthreads();

  float m2p[16];
  #pragma unroll
  for (int j=0;j<16;j++) m2p[j]=-1e30f;

  for (int i=wv; i<LCC; i+=4){
    const float* crow = ctx_out + ((size_t)b*LCC+i)*D2;
    float u1p=0.f, s1p=0.f, accj[16];
    #pragma unroll
    for (int j=0;j<16;j++) accj[j]=0.f;
    for (int m=0;m<10;m++){
      int d = lane + m*64;
      if (d<600){
        float v = crow[d];
        u1p = fmaf(v,w1s[d],u1p);
        s1p = fmaf(v,v1s[d],s1p);
        float cw = v*w3s[d];
        #pragma unroll
        for (int j=0;j<16;j++) accj[j] = fmaf(cw,asp[j][d],accj[j]);
      }
    }
    #pragma unroll
    for (int off=32; off>0; off>>=1){
      u1p += __shfl_xor(u1p,off);
      s1p += __shfl_xor(s1p,off);
      #pragma unroll
      for (int j=0;j<16;j++) accj[j] += __shfl_xor(accj[j],off);
    }
    float mj=-1e30f;
    #pragma unroll
    for (int j=0;j<16;j++){
      float a = u2s[j]+accj[j];
      mj = fmaxf(mj,a);
      m2p[j] = fmaxf(m2p[j], u1p+accj[j]);
    }
    if (lane==0){ m1s[i]=u1p+mj; s1s[i]=s1p; }
  }
  if (lane<16) m2w[wv][lane]=m2p[lane];
  __syncthreads();

  {
    float x1 = (tid<128)? m1s[tid] : -1e30f;
    red[tid]=x1; __syncthreads();
    for (int s=128;s>0;s>>=1){ if (tid<s) red[tid]=fmaxf(red[tid],red[tid+s]); __syncthreads(); }
    float M1=red[0]; __syncthreads();
    float e1=(tid<128)?expf(x1-M1):0.f;
    red[tid]=e1; __syncthreads();
    for (int s=128;s>0;s>>=1){ if (tid<s) red[tid]+=red[tid+s]; __syncthreads(); }
    float S1=red[0]; __syncthreads();
    if (tid<128) alph[tid]=e1/S1;

    float x2 = (tid<128)? s1s[tid] : -1e30f;
    red[tid]=x2; __syncthreads();
    for (int s=128;s>0;s>>=1){ if (tid<s) red[tid]=fmaxf(red[tid],red[tid+s]); __syncthreads(); }
    float M2=red[0]; __syncthreads();
    float e2=(tid<128)?expf(x2-M2):0.f;
    red[tid]=e2; __syncthreads();
    for (int s=128;s>0;s>>=1){ if (tid<s) red[tid]+=red[tid+s]; __syncthreads(); }
    float S2=red[0]; __syncthreads();
    if (tid<128) a1s[tid]=e2/S2;
  }

  if (tid<16){
    float m=-1e30f;
    #pragma unroll
    for (int w=0;w<4;w++) m=fmaxf(m,m2w[w][tid]);
    m2f[tid]=u2s[tid]+m;
    float s=0.f;
    for (int d=0;d<600;d++) s = fmaf(asp[tid][d],v2s[d],s);
    s2s[tid]=s;
  }
  __syncthreads();
  if (tid==0){
    float M=-1e30f,S=0.f;
    for (int j=0;j<16;j++) M=fmaxf(M,m2f[j]);
    for (int j=0;j<16;j++){ float e=expf(m2f[j]-M); bet[j]=e; S+=e; }
    for (int j=0;j<16;j++) bet[j]/=S;
    M=-1e30f;S=0.f;
    for (int j=0;j<16;j++) M=fmaxf(M,s2s[j]);
    for (int j=0;j<16;j++){ float e=expf(s2s[j]-M); a2s[j]=e; S+=e; }
    for (int j=0;j<16;j++) a2s[j]/=S;
  }
  __syncthreads();

  {
    const bool has2 = (tid<88);
    float fa0=0,fa1=0,fa2=0, ca0=0,ca1=0,ca2=0;
    for (int i=0;i<LCC;i++){
      float al=alph[i], aa=a1s[i];
      const float* crow = ctx_out + ((size_t)b*LCC+i)*D2;
      float x0=crow[tid];      fa0=fmaf(al,x0,fa0); ca0=fmaf(aa,x0,ca0);
      float x1=crow[tid+256];  fa1=fmaf(al,x1,fa1); ca1=fmaf(aa,x1,ca1);
      if (has2){ float x2=crow[tid+512]; fa2=fmaf(al,x2,fa2); ca2=fmaf(aa,x2,ca2); }
    }
    feat[tid]=ca0;           feat[600+tid]=fa0;
    feat[tid+256]=ca1;       feat[600+tid+256]=fa1;
    if (has2){ feat[tid+512]=ca2; feat[600+tid+512]=fa2; }

    float fc0=0,fc1=0,fc2=0, cc0=0,cc1=0,cc2=0;
    for (int j=0;j<16;j++){
      float be=bet[j], a2=a2s[j];
      float x0=asp[j][tid];      fc0=fmaf(be,x0,fc0); cc0=fmaf(a2,x0,cc0);
      float x1=asp[j][tid+256];  fc1=fmaf(be,x1,fc1); cc1=fmaf(a2,x1,cc1);
      if (has2){ float x2=asp[j][tid+512]; fc2=fmaf(be,x2,fc2); cc2=fmaf(a2,x2,cc2); }
    }
    feat[1200+tid]=fc0;        feat[1800+tid]=cc0;
    feat[1200+tid+256]=fc1;    feat[1800+tid+256]=cc1;
    if (has2){ feat[1200+tid+512]=fc2; feat[1800+tid+512]=cc2; }
  }
  __syncthreads();

  {
    float p0=0,p1=0,p2=0;
    for (int e=tid;e<2400;e+=256){
      float f=feat[e];
      p0=fmaf(f,dW[e],p0); p1=fmaf(f,dW[2400+e],p1); p2=fmaf(f,dW[4800+e],p2);
    }
    red[tid]=p0; __syncthreads();
    for (int s=128;s>0;s>>=1){ if (tid<s) red[tid]+=red[tid+s]; __syncthreads(); }
    if (tid==0) out[b*3+0]=red[0]+db[0];
    __syncthreads();
    red[tid]=p1; __syncthreads();
    for (int s=128;s>0;s>>=1){ if (tid<s) red[tid]+=red[tid+s]; __syncthreads(); }
    if (tid==0) out[b*3+1]=red[0]+db[1];
    __syncthreads();
    red[tid]=p2; __syncthreads();
    for (int s=128;s>0;s>>=1){ if (tid<s) red[tid]+=red[tid+s]; __syncthreads(); }
    if (tid==0) out[b*3+2]=red[0]+db[2];
  }
}

extern "C" void kernel_launch(void* const* d_in, const int* in_sizes, int n_in,
                              void* d_out, int out_size, void* d_ws, size_t ws_size,
                              hipStream_t stream) {
  const int*   traw =(const int*)d_in[0];
  const int*   tasp =(const int*)d_in[1];
  const int*   tleft=(const int*)d_in[2];
  const float* embed=(const float*)d_in[3];
  const float* cWif=(const float*)d_in[4];
  const float* cWhf=(const float*)d_in[5];
  const float* cbf =(const float*)d_in[6];
  const float* cWib=(const float*)d_in[7];
  const float* cWhb=(const float*)d_in[8];
  const float* cbb =(const float*)d_in[9];
  const float* aWif=(const float*)d_in[10];
  const float* aWhf=(const float*)d_in[11];
  const float* abf =(const float*)d_in[12];
  const float* aWib=(const float*)d_in[13];
  const float* aWhb=(const float*)d_in[14];
  const float* abb =(const float*)d_in[15];
  const float* w_u =(const float*)d_in[16];
  const float* w_a2c=(const float*)d_in[17];
  const float* w_c2a=(const float*)d_in[18];
  const float* dW  =(const float*)d_in[19];
  const float* db  =(const float*)d_in[20];
  float* out = (float*)d_out;

  char* w = (char*)d_ws;
  size_t o = 0;
  float* ctx_out  = (float*)(w+o); o += (size_t)BB*LCC*D2*4;          // 157,286,400
  float* asp_out  = (float*)(w+o); o += (size_t)BB*LAA*D2*4;          //  19,660,800
  char*  Wshare   = (char*)(w+o);  o += (size_t)11520000;             // max(Wfrag 9.83MB, WT4 11.52MB)
  float* ctx_pool = (float*)(w+o); o += (size_t)BB*D2*4;
  float* asp_pool = (float*)(w+o); o += (size_t)BB*D2*4;
  float* v1       = (float*)(w+o); o += (size_t)BB*D2*4;
  float* v2       = (float*)(w+o); o += (size_t)BB*D2*4;
  int*   clen     = (int*)(w+o);   o += (size_t)BB*4;
  int*   alen_    = (int*)(w+o);   o += (size_t)BB*4;
  int*   sstart   = (int*)(w+o);   o += (size_t)BB*4;
  float* bias_p   = (float*)(w+o); o += (size_t)4*NP*4;
  short* xg_all   = (short*)(w+o); o += (2*J0 + 2*J1)*2;              // 377,487,360
  const int use_mfma = (ws_size >= o) ? 1 : 0;

  hipMemsetAsync(ctx_out, 0, (size_t)BB*LCC*D2*4 + (size_t)BB*LAA*D2*4, stream);

  k_lengths<<<4,128,0,stream>>>(traw,tasp,tleft,clen,alen_,sstart);

  if (use_mfma){
    k_prep_frag<<<dim3(NT*KT,12),64,0,stream>>>(cWif,cWhf,cWib,cWhb,aWif,aWhf,aWib,aWhb,(short*)Wshare);
    k_prep_bias<<<dim3(4,5),256,0,stream>>>(cbf,cbb,abf,abb,bias_p);
    k_xg<<<4608,512,0,stream>>>(traw,tasp,embed,(const short*)Wshare,bias_p,clen,alen_,xg_all);
    k_rec_mfma<<<128,512,0,stream>>>((const short*)Wshare,(const short*)xg_all,
                                     clen,alen_,sstart,ctx_out,asp_out);
  } else {
    k_prep_f32<<<dim3(352,1,8),256,0,stream>>>(cWif,cWhf,cWib,cWhb,aWif,aWhf,aWib,aWhb,(float*)Wshare);
    k_rec_f32<<<256,512,0,stream>>>(traw,tasp,embed,(const float*)Wshare,
                                    cbf,cbb,abf,abb,clen,alen_,sstart,ctx_out,asp_out);
  }

  k_pool<<<512,256,0,stream>>>(ctx_out,asp_out,clen,alen_,ctx_pool,asp_pool);
  k_v1v2<<<512,256,0,stream>>>(w_a2c,w_c2a,ctx_pool,asp_pool,v1,v2);
  k_attn<<<512,256,0,stream>>>(ctx_out,asp_out,v1,v2,w_u,dW,db,out);
}